// Round 9
// baseline (798.725 us; speedup 1.0000x reference)
//
#include <hip/hip_runtime.h>

// ============================================================================
// ROUND 9: GEMM v3. r8 postmortem: persistent-B got 37.4->30.6us/layer only —
// 1:1 ds_read:MFMA inner loop at just 8 waves/CU (64KB LDS -> 2 blocks/CU)
// leaves latency exposed. Changes: (1) BN 64->32 (32KB LDS) + bounds(256,4)
// -> 4 blocks/CU = 16 waves/CU; (2) grid 1000 flat + bijective XCD swizzle
// (wg=(d%8)*125+d/8; bx=wg>>3, by=wg&7) -> per-XCD: ~16 consecutive row-
// panels x all W (1.3MB g + 256KB W, L2-resident) so the 8x A re-read stays
// in L2; (3) keep A software-pipeline, one barrier total.
// Prediction: gemm -> 10-14us/layer; total 761.5 -> ~700-715.
// Ledger: fixed harness fills ~400, gather 95 (floor), mega ~100, scan+fill
// ~50, gemm the largest controllable piece.
// ============================================================================

#define N_NODES 20000
#define S_COLS  4096
#define E_EDGES 640000
#define D_DIM   256

typedef unsigned short bf16_t;
typedef __attribute__((ext_vector_type(8))) short short8;
typedef __attribute__((ext_vector_type(4))) float f32x4;

__device__ __forceinline__ float bf2f(bf16_t u) {
    union { unsigned int i; float f; } v; v.i = ((unsigned int)u) << 16; return v.f;
}
__device__ __forceinline__ bf16_t f2bf(float x) {   // round-to-nearest-even
    union { float f; unsigned int i; } v; v.f = x;
    unsigned int r = v.i + 0x7FFF + ((v.i >> 16) & 1);
    return (bf16_t)(r >> 16);
}
__device__ __forceinline__ float lo_bf(unsigned int u) {
    union { unsigned int i; float f; } v; v.i = u << 16; return v.f;
}
__device__ __forceinline__ float hi_bf(unsigned int u) {
    union { unsigned int i; float f; } v; v.i = u & 0xFFFF0000u; return v.f;
}
__device__ __forceinline__ unsigned int pack_bf(float a, float b) {
    return (unsigned int)f2bf(a) | ((unsigned int)f2bf(b) << 16);
}

// ---------------------------------------------------------------------------
// MEGA front-end (r7, kept): blocks [0,5000) h0 wave-per-row x4,
// [5000,7500) edge count, [7500,7756) wsplit.
// ---------------------------------------------------------------------------
__global__ void __launch_bounds__(256, 4)
mega_kernel(const float* __restrict__ init_m,
            const float* __restrict__ w1, const float* __restrict__ b1,
            const float* __restrict__ w2, const float* __restrict__ b2,
            bf16_t* __restrict__ h,
            const int* __restrict__ eidx, int* __restrict__ cnt,
            const float* __restrict__ W,
            bf16_t* __restrict__ Wt_hi, bf16_t* __restrict__ Wt_lo) {
    int b = blockIdx.x;
    int t = threadIdx.x;

    if (b >= 5000) {
        int bb = b - 5000;
        if (bb < 2500) {                       // ---- edge count ----
            int e = bb * 256 + t;
            atomicAdd(&cnt[eidx[E_EDGES + e]], 1);
        } else {                               // ---- wsplit ----
            int k = bb - 2500;                 // 0..255
            float w = W[k * D_DIM + t];
            bf16_t hi = f2bf(w);
            bf16_t lo = f2bf(w - bf2f(hi));
            Wt_hi[t * D_DIM + k] = hi;
            Wt_lo[t * D_DIM + k] = lo;
        }
        return;
    }

    // ---- h0: wave-per-row ----
    __shared__ float w2s[16][256];             // 16 KB
#pragma unroll
    for (int k = 0; k < 16; ++k) w2s[k][t] = w2[k * D_DIM + t];
    __syncthreads();                           // only barrier in this branch

    int wave = t >> 6, lane = t & 63;
    int row  = b * 4 + wave;                   // 5000*4 = 20000 rows exactly

    float lw1[16], lb1[16];
#pragma unroll
    for (int k = 0; k < 16; ++k) { lw1[k] = w1[k]; lb1[k] = b1[k]; }

    const float4* rowp = (const float4*)(init_m + (size_t)row * S_COLS);
    float f[16] = {};
    float cn = 0.f;

#define PROC_COMP(val, jb)                                            \
    if ((val) != 0.f) {                                               \
        float jf = (float)(jb);                                       \
        _Pragma("unroll")                                             \
        for (int k = 0; k < 16; ++k)                                  \
            f[k] += fmaxf(jf * lw1[k] + lb1[k], 0.f);                 \
        cn += 1.f;                                                    \
    }

#pragma unroll 4
    for (int v = 0; v < 16; ++v) {
        float4 x = rowp[v * 64 + lane];
        int jb = (v * 64 + lane) * 4;
        PROC_COMP(x.x, jb)
        PROC_COMP(x.y, jb + 1)
        PROC_COMP(x.z, jb + 2)
        PROC_COMP(x.w, jb + 3)
    }
#undef PROC_COMP

    // 64-lane butterfly: every lane ends with the full-row sums
#pragma unroll
    for (int off = 32; off > 0; off >>= 1) {
#pragma unroll
        for (int k = 0; k < 16; ++k) f[k] += __shfl_xor(f[k], off, 64);
        cn += __shfl_xor(cn, off, 64);
    }

    // epilogue: lane -> cols [4*lane, 4*lane+4)
    float4 b2v = *(const float4*)(b2 + 4 * lane);
    float o0 = cn * b2v.x, o1 = cn * b2v.y, o2 = cn * b2v.z, o3 = cn * b2v.w;
#pragma unroll
    for (int k = 0; k < 16; ++k) {
        float4 wv = *(const float4*)(&w2s[k][4 * lane]);   // contiguous b128
        o0 += f[k] * wv.x;  o1 += f[k] * wv.y;
        o2 += f[k] * wv.z;  o3 += f[k] * wv.w;
    }
    float inv = 1.f / fmaxf(cn, 1.f);
    uint2 o;
    o.x = pack_bf(o0 * inv, o1 * inv);
    o.y = pack_bf(o2 * inv, o3 * inv);
    *(uint2*)(h + (size_t)row * D_DIM + 4 * lane) = o;
}

// ---------------------------------------------------------------------------
// CSC build: scan + fill (UNCHANGED)
// ---------------------------------------------------------------------------
__global__ void scan_kernel(const int* __restrict__ cnt, int* __restrict__ offs,
                            int* __restrict__ cur) {
    __shared__ int sdata[1024];
    int t = threadIdx.x;
    int base = t * 20;
    int vals[20];
    int local = 0;
#pragma unroll
    for (int k = 0; k < 20; ++k) {
        int idx = base + k;
        int v = (idx < N_NODES) ? cnt[idx] : 0;
        vals[k] = local;
        local += v;
    }
    sdata[t] = local;
    __syncthreads();
    for (int off = 1; off < 1024; off <<= 1) {
        int v = (t >= off) ? sdata[t - off] : 0;
        __syncthreads();
        sdata[t] += v;
        __syncthreads();
    }
    int prefix = (t == 0) ? 0 : sdata[t - 1];
#pragma unroll
    for (int k = 0; k < 20; ++k) {
        int idx = base + k;
        if (idx < N_NODES) {
            int o = prefix + vals[k];
            offs[idx] = o;
            cur[idx]  = o;
        }
    }
    if (t == 1023) offs[N_NODES] = sdata[1023];
}

__global__ void fill_kernel(const int* __restrict__ eidx, const float* __restrict__ attr,
                            int* __restrict__ cur, int* __restrict__ src_s,
                            float* __restrict__ attr_s) {
    int e = blockIdx.x * 256 + threadIdx.x;
    if (e < E_EDGES) {
        int r = eidx[e];
        int c = eidx[E_EDGES + e];
        int pos = atomicAdd(&cur[c], 1);
        src_s[pos]  = r;
        attr_s[pos] = attr[e];
    }
}

// ---------------------------------------------------------------------------
// Gather (UNCHANGED): g[c] = sum_e h[src[e]] * attr[e]
// ---------------------------------------------------------------------------
__global__ void gather_kernel(const bf16_t* __restrict__ h,
                              const int* __restrict__ offs,
                              const int* __restrict__ src_s,
                              const float* __restrict__ attr_s,
                              bf16_t* __restrict__ g) {
    int wid  = (blockIdx.x * blockDim.x + threadIdx.x) >> 6;
    int lane = threadIdx.x & 63;
    if (wid >= N_NODES) return;
    int half = lane >> 5;
    int l32  = lane & 31;
    int e0 = offs[wid], e1 = offs[wid + 1];

    float acc[8] = {};
    for (int base = e0; base < e1; base += 64) {
        int n = e1 - base; if (n > 64) n = 64;
        int   r_l = 0; float a_l = 0.f;
        if (lane < n) { r_l = src_s[base + lane]; a_l = attr_s[base + lane]; }
        int nn = (n + 15) & ~15;            // pad to 8 pair-iterations
        for (int q = 0; q < nn; q += 16) {
#pragma unroll
            for (int u = 0; u < 8; ++u) {
                int   sl = q + 2 * u + half;
                int   r  = __shfl(r_l, sl, 64);
                float a  = __shfl(a_l, sl, 64);
                uint4 v  = ((const uint4*)(h + (size_t)r * D_DIM))[l32];
                acc[0] += lo_bf(v.x) * a;  acc[1] += hi_bf(v.x) * a;
                acc[2] += lo_bf(v.y) * a;  acc[3] += hi_bf(v.y) * a;
                acc[4] += lo_bf(v.z) * a;  acc[5] += hi_bf(v.z) * a;
                acc[6] += lo_bf(v.w) * a;  acc[7] += hi_bf(v.w) * a;
            }
        }
    }
#pragma unroll
    for (int i = 0; i < 8; ++i) acc[i] += __shfl_xor(acc[i], 32, 64);

    if (half == 0) {
        uint4 o;
        o.x = pack_bf(acc[0], acc[1]);
        o.y = pack_bf(acc[2], acc[3]);
        o.z = pack_bf(acc[4], acc[5]);
        o.w = pack_bf(acc[6], acc[7]);
        ((uint4*)(g + (size_t)wid * D_DIM))[l32] = o;
    }
}

// ---------------------------------------------------------------------------
// GEMM v3: h' = relu(g @ W), persistent-B, BN=32, 16 waves/CU, XCD-swizzled.
// Block = 32 cols x 160 rows. W slab (hi+lo, 32KB) staged to LDS once
// (swizzled, 1 barrier); 10 M-tiles of 16 rows: A prefetch pipelined with
// 32 ds_read_b128 + 32 MFMA per tile. 4 blocks/CU (128KB LDS, VGPR<=128).
// ---------------------------------------------------------------------------
__global__ void __launch_bounds__(256, 4)
gemm_relu_kernel(const bf16_t* __restrict__ g,
                 const bf16_t* __restrict__ Wt_hi,
                 const bf16_t* __restrict__ Wt_lo,
                 bf16_t* __restrict__ hdst, float* __restrict__ fdst) {
    __shared__ bf16_t Bs[32][512];           // 32 KB: [n][k: 0..255 hi | 256..511 lo]
    int tid  = threadIdx.x;
    int w    = tid >> 6;
    int lane = tid & 63;
    int quad = lane >> 4;
    int id16 = lane & 15;

    // bijective XCD swizzle (m204): XCD j holds ~16 consecutive row-panels
    // x all 8 col-slabs -> g panel (1.3MB) + W (256KB) L2-resident per XCD.
    int d  = blockIdx.x;                     // 0..999
    int wg = (d & 7) * 125 + (d >> 3);
    int bx = wg >> 3;                        // 0..124 row-panel
    int by = wg & 7;                         // 0..7   col-slab
    int bn   = by * 32;
    int bm0  = bx * 160;                     // 125*160 = 20000: rows < N_NODES

    char* bs = (char*)Bs;

    // ---- stage W slab into LDS (coalesced 128B runs; swizzled dest) ----
    {
        int n  = tid >> 3;                   // 0..31
        int s0 = tid & 7;                    // 0..7
#pragma unroll
        for (int it = 0; it < 8; ++it) {
            int seg = s0 + it * 8;           // 0..63 (16B segments of 1KB row)
            const bf16_t* src = (seg < 32 ? Wt_hi : Wt_lo)
                              + (size_t)(bn + n) * D_DIM + (seg & 31) * 8;
            unsigned off = (unsigned)(n * 1024 + seg * 16) ^ (unsigned)((n & 7) << 4);
            *(uint4*)(bs + off) = *(const uint4*)src;
        }
    }

    // first-tile A prefetch (LDS-independent, issued before the barrier)
    int r0 = bm0 + w * 16;
    const bf16_t* arow = g + (size_t)(r0 + id16) * D_DIM;
    short8 areg[8];
#pragma unroll
    for (int i = 0; i < 8; ++i)
        areg[i] = *(const short8*)(arow + i * 32 + quad * 8);

    __syncthreads();                         // the only barrier

    unsigned swz   = (unsigned)((id16 & 7) << 4);
    unsigned nbase = (unsigned)(id16 * 1024);

    for (int t = w; t < 10; t += 4) {
        // software-pipeline: issue next tile's A loads before compute
        short8 anext[8];
        int tn = t + 4;
        if (tn < 10) {
            const bf16_t* an = g + (size_t)(bm0 + tn * 16 + id16) * D_DIM;
#pragma unroll
            for (int i = 0; i < 8; ++i)
                anext[i] = *(const short8*)(an + i * 32 + quad * 8);
        }

        f32x4 acc[2];
#pragma unroll
        for (int nt = 0; nt < 2; ++nt) acc[nt] = (f32x4){0.f, 0.f, 0.f, 0.f};

#pragma unroll
        for (int ks = 0; ks < 8; ++ks) {
            short8 a = areg[ks];
            unsigned kb = ((unsigned)(ks * 64 + quad * 16)) ^ swz;
#pragma unroll
            for (int nt = 0; nt < 2; ++nt) {
                unsigned off = (unsigned)(nt * 16384) + nbase + kb;
                short8 bh = *(const short8*)(bs + off);         // hi plane
                short8 bl = *(const short8*)(bs + off + 512);   // lo plane
                acc[nt] = __builtin_amdgcn_mfma_f32_16x16x32_bf16(a, bh, acc[nt], 0, 0, 0);
                acc[nt] = __builtin_amdgcn_mfma_f32_16x16x32_bf16(a, bl, acc[nt], 0, 0, 0);
            }
        }

        int mrow = bm0 + t * 16;
#pragma unroll
        for (int nt = 0; nt < 2; ++nt) {
#pragma unroll
            for (int r = 0; r < 4; ++r) {
                int m = mrow + quad * 4 + r;         // < 20000 by construction
                int n = bn + nt * 16 + id16;
                float v = fmaxf(acc[nt][r], 0.f);
                if (hdst) hdst[(size_t)m * D_DIM + n] = f2bf(v);
                else      fdst[(size_t)m * D_DIM + n] = v;
            }
        }
#pragma unroll
        for (int i = 0; i < 8; ++i) areg[i] = anext[i];
    }
}

extern "C" void kernel_launch(void* const* d_in, const int* in_sizes, int n_in,
                              void* d_out, int out_size, void* d_ws, size_t ws_size,
                              hipStream_t stream) {
    const float* init_m = (const float*)d_in[0];
    const int*   eidx   = (const int*)  d_in[1];
    const float* attr   = (const float*)d_in[2];
    const float* w1     = (const float*)d_in[3];
    const float* b1     = (const float*)d_in[4];
    const float* w2     = (const float*)d_in[5];
    const float* b2     = (const float*)d_in[6];
    const float* Wm     = (const float*)d_in[7];
    float* out = (float*)d_out;

    char* ws = (char*)d_ws;
    bf16_t* hbuf   = (bf16_t*)ws;                        // 10,240,000
    bf16_t* gbuf   = (bf16_t*)(ws + 10240000);           // 10,289,152 (incl pad rows)
    int*    cnt    = (int*)   (ws + 20529152);
    int*    offs   = (int*)   (ws + 20609152);
    int*    cur    = (int*)   (ws + 20689408);
    int*    src_s  = (int*)   (ws + 20769408);
    float*  attr_s = (float*) (ws + 23329408);
    bf16_t* Wt_hi  = (bf16_t*)(ws + 25889408);
    bf16_t* Wt_lo  = (bf16_t*)(ws + 26020480);

    // single memset covers gbuf pad rows + cnt
    hipMemsetAsync(ws + 20480000, 0, 129152, stream);

    // front-end: h0 (wave-per-row) + edge-count + wsplit in one dispatch
    mega_kernel<<<5000 + 2500 + 256, 256, 0, stream>>>(
        init_m, w1, b1, w2, b2, hbuf, eidx, cnt, Wm, Wt_hi, Wt_lo);
    scan_kernel<<<1, 1024, 0, stream>>>(cnt, offs, cur);
    fill_kernel<<<(E_EDGES + 255) / 256, 256, 0, stream>>>(eidx, attr, cur, src_s, attr_s);

    // 3x GCN layer: g = gather(h); h' = relu(g @ W)
    dim3 ggrid((N_NODES * 64 + 255) / 256);
    for (int it = 0; it < 3; ++it) {
        gather_kernel<<<ggrid, 256, 0, stream>>>(hbuf, offs, src_s, attr_s, gbuf);
        if (it == 2)
            gemm_relu_kernel<<<1000, 256, 0, stream>>>(gbuf, Wt_hi, Wt_lo,
                                                       (bf16_t*)nullptr, out);
        else
            gemm_relu_kernel<<<1000, 256, 0, stream>>>(gbuf, Wt_hi, Wt_lo,
                                                       hbuf, (float*)nullptr);
    }
}

// Round 10
// 694.301 us; speedup vs baseline: 1.1504x; 1.1504x over previous
//
#include <hip/hip_runtime.h>

// ============================================================================
// ROUND 10: GEMM v4 (dual-M-tile waves). r9 regressed (+37us): bounds(256,4)
// VGPR cap 128 with 64+ VGPR of A state -> spill/sched squeeze, and BN=32
// doubled A traffic. Revert geometry to r8 (BN=64, 64KB LDS, bounds(256,2)),
// fix the real stall instead: r8's inner loop was 1:1 ds_read:MFMA chains.
// v4: wave owns 32 rows (2 A-frag sets, 64 VGPR) -> each bh/bl LDS read
// feeds 4 MFMAs (1:2 ratio), one-shot per wave (no M-loop, A loads overlap
// W-stage before the single barrier). Block 128 rows x 64 cols; grid 628
// flat with bijective XCD chunking (4x79+4x78) so each XCD holds ~20
// consecutive row-panels x all 4 slabs (1.3MB g + 512KB W, L2-resident).
// Rows 157*128=20096: gbuf pad rows (zeroed) absorb overread; writes guarded.
// Prediction: gemm 30.6 -> 12-16us/layer; total 761.5 -> ~705-725.
// ============================================================================

#define N_NODES 20000
#define S_COLS  4096
#define E_EDGES 640000
#define D_DIM   256

typedef unsigned short bf16_t;
typedef __attribute__((ext_vector_type(8))) short short8;
typedef __attribute__((ext_vector_type(4))) float f32x4;

__device__ __forceinline__ float bf2f(bf16_t u) {
    union { unsigned int i; float f; } v; v.i = ((unsigned int)u) << 16; return v.f;
}
__device__ __forceinline__ bf16_t f2bf(float x) {   // round-to-nearest-even
    union { float f; unsigned int i; } v; v.f = x;
    unsigned int r = v.i + 0x7FFF + ((v.i >> 16) & 1);
    return (bf16_t)(r >> 16);
}
__device__ __forceinline__ float lo_bf(unsigned int u) {
    union { unsigned int i; float f; } v; v.i = u << 16; return v.f;
}
__device__ __forceinline__ float hi_bf(unsigned int u) {
    union { unsigned int i; float f; } v; v.i = u & 0xFFFF0000u; return v.f;
}
__device__ __forceinline__ unsigned int pack_bf(float a, float b) {
    return (unsigned int)f2bf(a) | ((unsigned int)f2bf(b) << 16);
}

// ---------------------------------------------------------------------------
// MEGA front-end (r7, kept): blocks [0,5000) h0 wave-per-row x4,
// [5000,7500) edge count, [7500,7756) wsplit.
// ---------------------------------------------------------------------------
__global__ void __launch_bounds__(256, 4)
mega_kernel(const float* __restrict__ init_m,
            const float* __restrict__ w1, const float* __restrict__ b1,
            const float* __restrict__ w2, const float* __restrict__ b2,
            bf16_t* __restrict__ h,
            const int* __restrict__ eidx, int* __restrict__ cnt,
            const float* __restrict__ W,
            bf16_t* __restrict__ Wt_hi, bf16_t* __restrict__ Wt_lo) {
    int b = blockIdx.x;
    int t = threadIdx.x;

    if (b >= 5000) {
        int bb = b - 5000;
        if (bb < 2500) {                       // ---- edge count ----
            int e = bb * 256 + t;
            atomicAdd(&cnt[eidx[E_EDGES + e]], 1);
        } else {                               // ---- wsplit ----
            int k = bb - 2500;                 // 0..255
            float w = W[k * D_DIM + t];
            bf16_t hi = f2bf(w);
            bf16_t lo = f2bf(w - bf2f(hi));
            Wt_hi[t * D_DIM + k] = hi;
            Wt_lo[t * D_DIM + k] = lo;
        }
        return;
    }

    // ---- h0: wave-per-row ----
    __shared__ float w2s[16][256];             // 16 KB
#pragma unroll
    for (int k = 0; k < 16; ++k) w2s[k][t] = w2[k * D_DIM + t];
    __syncthreads();                           // only barrier in this branch

    int wave = t >> 6, lane = t & 63;
    int row  = b * 4 + wave;                   // 5000*4 = 20000 rows exactly

    float lw1[16], lb1[16];
#pragma unroll
    for (int k = 0; k < 16; ++k) { lw1[k] = w1[k]; lb1[k] = b1[k]; }

    const float4* rowp = (const float4*)(init_m + (size_t)row * S_COLS);
    float f[16] = {};
    float cn = 0.f;

#define PROC_COMP(val, jb)                                            \
    if ((val) != 0.f) {                                               \
        float jf = (float)(jb);                                       \
        _Pragma("unroll")                                             \
        for (int k = 0; k < 16; ++k)                                  \
            f[k] += fmaxf(jf * lw1[k] + lb1[k], 0.f);                 \
        cn += 1.f;                                                    \
    }

#pragma unroll 4
    for (int v = 0; v < 16; ++v) {
        float4 x = rowp[v * 64 + lane];
        int jb = (v * 64 + lane) * 4;
        PROC_COMP(x.x, jb)
        PROC_COMP(x.y, jb + 1)
        PROC_COMP(x.z, jb + 2)
        PROC_COMP(x.w, jb + 3)
    }
#undef PROC_COMP

    // 64-lane butterfly: every lane ends with the full-row sums
#pragma unroll
    for (int off = 32; off > 0; off >>= 1) {
#pragma unroll
        for (int k = 0; k < 16; ++k) f[k] += __shfl_xor(f[k], off, 64);
        cn += __shfl_xor(cn, off, 64);
    }

    // epilogue: lane -> cols [4*lane, 4*lane+4)
    float4 b2v = *(const float4*)(b2 + 4 * lane);
    float o0 = cn * b2v.x, o1 = cn * b2v.y, o2 = cn * b2v.z, o3 = cn * b2v.w;
#pragma unroll
    for (int k = 0; k < 16; ++k) {
        float4 wv = *(const float4*)(&w2s[k][4 * lane]);   // contiguous b128
        o0 += f[k] * wv.x;  o1 += f[k] * wv.y;
        o2 += f[k] * wv.z;  o3 += f[k] * wv.w;
    }
    float inv = 1.f / fmaxf(cn, 1.f);
    uint2 o;
    o.x = pack_bf(o0 * inv, o1 * inv);
    o.y = pack_bf(o2 * inv, o3 * inv);
    *(uint2*)(h + (size_t)row * D_DIM + 4 * lane) = o;
}

// ---------------------------------------------------------------------------
// CSC build: scan + fill (UNCHANGED)
// ---------------------------------------------------------------------------
__global__ void scan_kernel(const int* __restrict__ cnt, int* __restrict__ offs,
                            int* __restrict__ cur) {
    __shared__ int sdata[1024];
    int t = threadIdx.x;
    int base = t * 20;
    int vals[20];
    int local = 0;
#pragma unroll
    for (int k = 0; k < 20; ++k) {
        int idx = base + k;
        int v = (idx < N_NODES) ? cnt[idx] : 0;
        vals[k] = local;
        local += v;
    }
    sdata[t] = local;
    __syncthreads();
    for (int off = 1; off < 1024; off <<= 1) {
        int v = (t >= off) ? sdata[t - off] : 0;
        __syncthreads();
        sdata[t] += v;
        __syncthreads();
    }
    int prefix = (t == 0) ? 0 : sdata[t - 1];
#pragma unroll
    for (int k = 0; k < 20; ++k) {
        int idx = base + k;
        if (idx < N_NODES) {
            int o = prefix + vals[k];
            offs[idx] = o;
            cur[idx]  = o;
        }
    }
    if (t == 1023) offs[N_NODES] = sdata[1023];
}

__global__ void fill_kernel(const int* __restrict__ eidx, const float* __restrict__ attr,
                            int* __restrict__ cur, int* __restrict__ src_s,
                            float* __restrict__ attr_s) {
    int e = blockIdx.x * 256 + threadIdx.x;
    if (e < E_EDGES) {
        int r = eidx[e];
        int c = eidx[E_EDGES + e];
        int pos = atomicAdd(&cur[c], 1);
        src_s[pos]  = r;
        attr_s[pos] = attr[e];
    }
}

// ---------------------------------------------------------------------------
// Gather (UNCHANGED): g[c] = sum_e h[src[e]] * attr[e]
// ---------------------------------------------------------------------------
__global__ void gather_kernel(const bf16_t* __restrict__ h,
                              const int* __restrict__ offs,
                              const int* __restrict__ src_s,
                              const float* __restrict__ attr_s,
                              bf16_t* __restrict__ g) {
    int wid  = (blockIdx.x * blockDim.x + threadIdx.x) >> 6;
    int lane = threadIdx.x & 63;
    if (wid >= N_NODES) return;
    int half = lane >> 5;
    int l32  = lane & 31;
    int e0 = offs[wid], e1 = offs[wid + 1];

    float acc[8] = {};
    for (int base = e0; base < e1; base += 64) {
        int n = e1 - base; if (n > 64) n = 64;
        int   r_l = 0; float a_l = 0.f;
        if (lane < n) { r_l = src_s[base + lane]; a_l = attr_s[base + lane]; }
        int nn = (n + 15) & ~15;            // pad to 8 pair-iterations
        for (int q = 0; q < nn; q += 16) {
#pragma unroll
            for (int u = 0; u < 8; ++u) {
                int   sl = q + 2 * u + half;
                int   r  = __shfl(r_l, sl, 64);
                float a  = __shfl(a_l, sl, 64);
                uint4 v  = ((const uint4*)(h + (size_t)r * D_DIM))[l32];
                acc[0] += lo_bf(v.x) * a;  acc[1] += hi_bf(v.x) * a;
                acc[2] += lo_bf(v.y) * a;  acc[3] += hi_bf(v.y) * a;
                acc[4] += lo_bf(v.z) * a;  acc[5] += hi_bf(v.z) * a;
                acc[6] += lo_bf(v.w) * a;  acc[7] += hi_bf(v.w) * a;
            }
        }
    }
#pragma unroll
    for (int i = 0; i < 8; ++i) acc[i] += __shfl_xor(acc[i], 32, 64);

    if (half == 0) {
        uint4 o;
        o.x = pack_bf(acc[0], acc[1]);
        o.y = pack_bf(acc[2], acc[3]);
        o.z = pack_bf(acc[4], acc[5]);
        o.w = pack_bf(acc[6], acc[7]);
        ((uint4*)(g + (size_t)wid * D_DIM))[l32] = o;
    }
}

// ---------------------------------------------------------------------------
// GEMM v4: h' = relu(g @ W), persistent-B, dual-M-tile waves.
// Block = 128 rows x 64 cols, 4 waves, each wave 32 rows (2 A-frag sets) x
// 64 cols. W quarter (hi+lo, 64KB) staged once (swizzled, 1 barrier); then
// per wave: 8ks x 4nt x {2 ds_read_b128, 4 MFMA} — 1:2 read:MFMA, one-shot.
// A loads issue before the barrier (overlap W stage). bounds(256,2): no
// VGPR trap (areg 64 + acc 32 + addr < 256).
// ---------------------------------------------------------------------------
__global__ void __launch_bounds__(256, 2)
gemm_relu_kernel(const bf16_t* __restrict__ g,
                 const bf16_t* __restrict__ Wt_hi,
                 const bf16_t* __restrict__ Wt_lo,
                 bf16_t* __restrict__ hdst, float* __restrict__ fdst) {
    __shared__ bf16_t Bs[64][512];           // 64 KB: [n][k: 0..255 hi | 256..511 lo]
    int tid  = threadIdx.x;
    int w    = tid >> 6;
    int lane = tid & 63;
    int quad = lane >> 4;
    int id16 = lane & 15;

    // bijective XCD chunking over 628 blocks (4 XCDs x 79 + 4 x 78):
    // each XCD holds ~20 consecutive row-panels x all 4 col-slabs.
    int d    = blockIdx.x;                   // 0..627
    int xcd  = d & 7;
    int base = (xcd < 4) ? xcd * 79 : 316 + (xcd - 4) * 78;
    int wg   = base + (d >> 3);
    int bx   = wg >> 2;                      // 0..156 row-panel
    int by   = wg & 3;                       // 0..3   col-slab
    int bn   = by * 64;
    int bm0  = bx * 128;                     // up to 20096: gbuf pad absorbs

    char* bs = (char*)Bs;

    // ---- stage W quarter into LDS (r8 pattern, swizzled dest) ----
    {
        int tn0 = tid >> 4;                  // 0..15
        int ts0 = tid & 15;                  // 0..15
#pragma unroll
        for (int it = 0; it < 16; ++it) {
            int n   = tn0 + (it & 3) * 16;   // 0..63
            int seg = ts0 + (it >> 2) * 16;  // 0..63 (16B segments of 1KB row)
            const bf16_t* src = (seg < 32 ? Wt_hi : Wt_lo)
                              + (size_t)(bn + n) * D_DIM + (seg & 31) * 8;
            unsigned off = (unsigned)(n * 1024 + seg * 16) ^ (unsigned)((n & 7) << 4);
            *(uint4*)(bs + off) = *(const uint4*)src;
        }
    }

    // ---- A loads: two 16-row fragment sets (issued before the barrier) ----
    int r0 = bm0 + w * 32;
    short8 areg[2][8];
#pragma unroll
    for (int j = 0; j < 2; ++j) {
        const bf16_t* arow = g + (size_t)(r0 + j * 16 + id16) * D_DIM;
#pragma unroll
        for (int i = 0; i < 8; ++i)
            areg[j][i] = *(const short8*)(arow + i * 32 + quad * 8);
    }

    __syncthreads();                         // the only barrier

    unsigned swz   = (unsigned)((id16 & 7) << 4);
    unsigned nbase = (unsigned)(id16 * 1024);

    f32x4 acc[2][4];
#pragma unroll
    for (int j = 0; j < 2; ++j)
#pragma unroll
        for (int nt = 0; nt < 4; ++nt) acc[j][nt] = (f32x4){0.f, 0.f, 0.f, 0.f};

#pragma unroll
    for (int ks = 0; ks < 8; ++ks) {
        unsigned kb = ((unsigned)(ks * 64 + quad * 16)) ^ swz;
#pragma unroll
        for (int nt = 0; nt < 4; ++nt) {
            unsigned off = (unsigned)(nt * 16384) + nbase + kb;
            short8 bh = *(const short8*)(bs + off);         // hi plane
            short8 bl = *(const short8*)(bs + off + 512);   // lo plane
            acc[0][nt] = __builtin_amdgcn_mfma_f32_16x16x32_bf16(areg[0][ks], bh, acc[0][nt], 0, 0, 0);
            acc[0][nt] = __builtin_amdgcn_mfma_f32_16x16x32_bf16(areg[0][ks], bl, acc[0][nt], 0, 0, 0);
            acc[1][nt] = __builtin_amdgcn_mfma_f32_16x16x32_bf16(areg[1][ks], bh, acc[1][nt], 0, 0, 0);
            acc[1][nt] = __builtin_amdgcn_mfma_f32_16x16x32_bf16(areg[1][ks], bl, acc[1][nt], 0, 0, 0);
        }
    }

    // epilogue: relu + store (guarded: rows 20000..20095 are pad)
#pragma unroll
    for (int j = 0; j < 2; ++j) {
#pragma unroll
        for (int nt = 0; nt < 4; ++nt) {
#pragma unroll
            for (int r = 0; r < 4; ++r) {
                int m = r0 + j * 16 + quad * 4 + r;
                if (m < N_NODES) {
                    int n = bn + nt * 16 + id16;
                    float v = fmaxf(acc[j][nt][r], 0.f);
                    if (hdst) hdst[(size_t)m * D_DIM + n] = f2bf(v);
                    else      fdst[(size_t)m * D_DIM + n] = v;
                }
            }
        }
    }
}

extern "C" void kernel_launch(void* const* d_in, const int* in_sizes, int n_in,
                              void* d_out, int out_size, void* d_ws, size_t ws_size,
                              hipStream_t stream) {
    const float* init_m = (const float*)d_in[0];
    const int*   eidx   = (const int*)  d_in[1];
    const float* attr   = (const float*)d_in[2];
    const float* w1     = (const float*)d_in[3];
    const float* b1     = (const float*)d_in[4];
    const float* w2     = (const float*)d_in[5];
    const float* b2     = (const float*)d_in[6];
    const float* Wm     = (const float*)d_in[7];
    float* out = (float*)d_out;

    char* ws = (char*)d_ws;
    bf16_t* hbuf   = (bf16_t*)ws;                        // 10,240,000
    bf16_t* gbuf   = (bf16_t*)(ws + 10240000);           // 10,289,152 (incl 96 pad rows)
    int*    cnt    = (int*)   (ws + 20529152);
    int*    offs   = (int*)   (ws + 20609152);
    int*    cur    = (int*)   (ws + 20689408);
    int*    src_s  = (int*)   (ws + 20769408);
    float*  attr_s = (float*) (ws + 23329408);
    bf16_t* Wt_hi  = (bf16_t*)(ws + 25889408);
    bf16_t* Wt_lo  = (bf16_t*)(ws + 26020480);

    // single memset covers gbuf pad rows (20,480,000..20,529,152) + cnt
    hipMemsetAsync(ws + 20480000, 0, 129152, stream);

    // front-end: h0 (wave-per-row) + edge-count + wsplit in one dispatch
    mega_kernel<<<5000 + 2500 + 256, 256, 0, stream>>>(
        init_m, w1, b1, w2, b2, hbuf, eidx, cnt, Wm, Wt_hi, Wt_lo);
    scan_kernel<<<1, 1024, 0, stream>>>(cnt, offs, cur);
    fill_kernel<<<(E_EDGES + 255) / 256, 256, 0, stream>>>(eidx, attr, cur, src_s, attr_s);

    // 3x GCN layer: g = gather(h); h' = relu(g @ W)
    dim3 ggrid((N_NODES * 64 + 255) / 256);
    for (int it = 0; it < 3; ++it) {
        gather_kernel<<<ggrid, 256, 0, stream>>>(hbuf, offs, src_s, attr_s, gbuf);
        if (it == 2)
            gemm_relu_kernel<<<628, 256, 0, stream>>>(gbuf, Wt_hi, Wt_lo,
                                                      (bf16_t*)nullptr, out);
        else
            gemm_relu_kernel<<<628, 256, 0, stream>>>(gbuf, Wt_hi, Wt_lo,
                                                      hbuf, (float*)nullptr);
    }
}